// Round 21
// baseline (66.788 us; speedup 1.0000x reference)
//
#include <hip/hip_runtime.h>
#include <hip/hip_bf16.h>
#include <stdint.h>
#include <stddef.h>

#define BATCH 4
#define SEQ   2048
#define DM    512
#define NST   64
#define LN_EPS 1e-5f
#define NCH   32    // 32 chunks of 64
#define KDIM  192   // 64 x-taps + 128 carry (re,im interleaved)

typedef __attribute__((ext_vector_type(8))) short short8;
typedef __attribute__((ext_vector_type(4))) float f32x4;

__device__ __forceinline__ ushort f2bf(float f) {
    __hip_bfloat16 h = __float2bfloat16(f);
    return *(ushort*)&h;
}
__device__ __forceinline__ float bf2f(ushort u) {
    __hip_bfloat16 h = *(__hip_bfloat16*)&u;
    return __bfloat162float(h);
}

// ---------------- k_prep: fused  x-transpose | W-convert | M+G build ----------------
// blocks [0,2048):    x[b][l][d] f32 -> xT[d][b][l] bf16
// blocks [2048,3072): W->bf16
// blocks [3072,3200): per-d FIR/carry matrix M[64][192] bf16  +  G[128][64] bf16 + eA^64
__global__ __launch_bounds__(256) void k_prep(
    const float* __restrict__ x,
    const float* __restrict__ logA, const float* __restrict__ Aim,
    const float* __restrict__ Bp, const float* __restrict__ Cp,
    const float* __restrict__ W,
    __hip_bfloat16* __restrict__ xT,
    __hip_bfloat16* __restrict__ Wbf, __hip_bfloat16* __restrict__ Mt,
    __hip_bfloat16* __restrict__ Gt, float2* __restrict__ e64)
{
    __shared__ float smem[64][33];
    const int tid = threadIdx.x;
    const int bid = blockIdx.x;

    if (bid < 2048) {
        const int dt = bid & 15, lt = (bid >> 4) & 31, b = bid >> 9;
        const int l0 = lt * 64, d0 = dt * 32;
        const int dd = tid & 31, lr = tid >> 5;
        #pragma unroll
        for (int it = 0; it < 8; ++it) {
            int ll = it * 8 + lr;
            smem[ll][dd] = x[((size_t)b * SEQ + l0 + ll) * DM + d0 + dd];
        }
        __syncthreads();
        const int dw = tid >> 3, lg = (tid & 7) * 8;
        ushort pk[8];
        #pragma unroll
        for (int i = 0; i < 8; ++i) pk[i] = f2bf(smem[lg + i][dw]);
        *(short8*)&xT[((size_t)(d0 + dw) * BATCH + b) * SEQ + l0 + lg] = *(short8*)pk;
    } else if (bid < 3072) {
        int i = (bid - 2048) * 256 + tid;
        if (i < DM * DM) Wbf[i] = __float2bfloat16(W[i]);
    } else {
        // M[i][j] = K[j-i] (j>=i else 0); M[i][64+2s] = Re(eA_s^(64-i)); M[i][65+2s] = -Im
        // G[2s][t] = Re(eA^t CB), G[2s+1][t] = Im(eA^t CB); e64 = eA^64
        float (*Klds)[64] = (float(*)[64])smem;
        const int w = tid >> 6, lane = tid & 63;
        const int d = (bid - 3072) * 4 + w;
        const int i = d * NST + lane;
        float aa  = expf(logA[i]);
        float wim = Aim[i];
        float mag = expf(-aa);
        float er = mag * cosf(wim), ei = mag * sinf(wim);
        float Br = Bp[2*i], Bi = Bp[2*i+1];
        float Cr = Cp[2*i], Ci = Cp[2*i+1];
        float pr = Cr*Br + Ci*Bi;                 // CB * eA^t (t=0)
        float pi = Cr*Bi - Ci*Br;
        float ar = 1.f, ai = 0.f;                 // eA^t
        __hip_bfloat16* Md = Mt + (size_t)d * 64 * KDIM;
        __hip_bfloat16* Gr = Gt + ((size_t)d * 128 + 2 * lane) * 64;       // re row
        __hip_bfloat16* Gi = Gt + ((size_t)d * 128 + 2 * lane + 1) * 64;   // im row
        for (int tb = 0; tb < 8; ++tb) {
            ushort bufR[8], bufI[8];
            #pragma unroll
            for (int tt = 0; tt < 8; ++tt) {
                const int t = tb * 8 + tt;
                float kv = pr;
                #pragma unroll
                for (int mask = 1; mask < 64; mask <<= 1) kv += __shfl_xor(kv, mask);
                if (lane == 0) Klds[w][t] = kv;
                bufR[tt] = f2bf(pr);              // G row values at k=t
                bufI[tt] = f2bf(pi);
                float npr = er*pr - ei*pi, npi = er*pi + ei*pr;  pr = npr; pi = npi;
                float nar = er*ar - ei*ai, nai = er*ai + ei*ar;  ar = nar; ai = nai;
                uint u = (uint)f2bf(ar) | ((uint)f2bf(-ai) << 16);
                *(uint*)&Md[(63 - t) * KDIM + 64 + 2 * lane] = u;   // row 64-(t+1)
            }
            *(short8*)&Gr[tb * 8] = *(short8*)bufR;
            *(short8*)&Gi[tb * 8] = *(short8*)bufI;
        }
        e64[(size_t)d * NST + lane] = make_float2(ar, ai);   // eA^64
        __syncthreads();
        for (int r = 0; r < 64; ++r) {
            float v = (lane >= r) ? Klds[w][lane - r] : 0.f;
            Md[r * KDIM + lane] = __float2bfloat16(v);
        }
    }
}

// ---------------- k_ssm: merged scanU + gemmY (per-d block; carries never leave LDS) ----------------
__global__ __launch_bounds__(256) void k_ssm(
    const __hip_bfloat16* __restrict__ Gt, const __hip_bfloat16* __restrict__ Mt,
    const __hip_bfloat16* __restrict__ xT, const float2* __restrict__ e64,
    const float* __restrict__ Dp, __hip_bfloat16* __restrict__ yT)
{
    __shared__ short Zs[128 * 24 * 8];            // 48K persistent: x chunks 0-7, carry chunks 8-23
    __shared__ __align__(16) char Rgn[16384 + 128 * 129 * 4];   // union: {Gs 16K + Us 64.5K} / {Ms 24K}
    short* Gs = (short*)Rgn;
    float (*Us)[129] = (float(*)[129])(Rgn + 16384);
    short* Ms = (short*)Rgn;

    const int tid = threadIdx.x;
    const int d = blockIdx.x;
    const int w = tid >> 6, lane = tid & 63;
    const int q = lane >> 4, n = lane & 15;

    // ---- stage Gs (128 rows x 8 chunks) and Zs x-part (128 cols x 8 chunks) ----
    {
        const short* Gg = (const short*)(Gt + (size_t)d * 128 * 64);
        #pragma unroll
        for (int it = 0; it < 4; ++it) {
            int Gc = it * 256 + tid;
            int row = Gc >> 3, c = Gc & 7;
            int cs = c ^ (row & 7);
            *(short8*)&Gs[(row * 8 + cs) * 8] = *(const short8*)&Gg[Gc * 8];
        }
        #pragma unroll
        for (int it = 0; it < 4; ++it) {
            int id = it * 256 + tid;
            int col = id >> 3, ck = id & 7;
            int bb = col >> 5, ch = col & 31;
            short8 v = *(const short8*)&xT[((size_t)d * BATCH + bb) * SEQ + ch * 64 + ck * 8];
            int cs = ck ^ (col & 7);
            *(short8*)&Zs[(col * 24 + cs) * 8] = v;
        }
    }
    __syncthreads();

    // ---- phase 1: U = G * X ----
    {
        f32x4 acc[2][8];
        #pragma unroll
        for (int rt = 0; rt < 2; ++rt)
            #pragma unroll
            for (int nf = 0; nf < 8; ++nf)
                #pragma unroll
                for (int k = 0; k < 4; ++k) acc[rt][nf][k] = 0.f;

        #pragma unroll
        for (int rt = 0; rt < 2; ++rt) {
            const int arow = w * 32 + rt * 16 + n;
            #pragma unroll
            for (int kt = 0; kt < 2; ++kt) {
                int c = kt * 4 + q;
                int csa = c ^ (arow & 7);
                short8 af = *(const short8*)&Gs[(arow * 8 + csa) * 8];
                #pragma unroll
                for (int nf = 0; nf < 8; ++nf) {
                    int col = nf * 16 + n;
                    int csb = c ^ (col & 7);
                    short8 bf = *(const short8*)&Zs[(col * 24 + csb) * 8];
                    acc[rt][nf] = __builtin_amdgcn_mfma_f32_16x16x32_bf16(af, bf, acc[rt][nf], 0, 0, 0);
                }
            }
        }
        #pragma unroll
        for (int rt = 0; rt < 2; ++rt) {
            const int r0w = w * 32 + rt * 16 + q * 4;
            #pragma unroll
            for (int nf = 0; nf < 8; ++nf) {
                int col = nf * 16 + n;
                #pragma unroll
                for (int r = 0; r < 4; ++r) Us[r0w + r][col] = acc[rt][nf][r];
            }
        }
    }
    __syncthreads();

    // ---- phase 2: carry combine, bf16 results straight into Zs carry chunks ----
    {
        const int bb = tid >> 6, s = tid & 63;
        const int st = s >> 2, so = (s & 3) * 2;        // chunk st, short offset within 16B
        float2 a64 = e64[(size_t)d * NST + s];
        const float er = a64.x, ei = a64.y;
        {
            int col = bb * 32 + 31;
            int c = 8 + st, cs = (c & ~7) | ((c & 7) ^ (col & 7));
            *(uint*)&Zs[(col * 24 + cs) * 8 + so] = 0u;
        }
        float gr = Us[2 * s][bb * 32 + 31], gi = Us[2 * s + 1][bb * 32 + 31];
        {
            int col = bb * 32 + 30;
            int c = 8 + st, cs = (c & ~7) | ((c & 7) ^ (col & 7));
            *(uint*)&Zs[(col * 24 + cs) * 8 + so] = (uint)f2bf(gr) | ((uint)f2bf(gi) << 16);
        }
        for (int ch = 30; ch >= 1; --ch) {
            float ur = Us[2 * s][bb * 32 + ch], ui = Us[2 * s + 1][bb * 32 + ch];
            float nr = ur + er * gr - ei * gi;
            float ni = ui + er * gi + ei * gr;
            gr = nr; gi = ni;
            int col = bb * 32 + ch - 1;
            int c = 8 + st, cs = (c & ~7) | ((c & 7) ^ (col & 7));
            *(uint*)&Zs[(col * 24 + cs) * 8 + so] = (uint)f2bf(gr) | ((uint)f2bf(gi) << 16);
        }
    }
    __syncthreads();

    // ---- stage Ms into the union region (Gs/Us dead now) ----
    {
        const short* Mg = (const short*)(Mt + (size_t)d * 64 * KDIM);
        #pragma unroll
        for (int it = 0; it < 6; ++it) {
            int G = it * 256 + tid;
            int row = G / 24, c = G % 24;
            int cs = (c & ~7) | ((c & 7) ^ (row & 7));
            *(short8*)&Ms[(row * 24 + cs) * 8] = *(const short8*)&Mg[G * 8];
        }
    }
    __syncthreads();

    // ---- phase 3: y = M * Z, + D*x, store yT ----
    f32x4 acc[8];
    #pragma unroll
    for (int nf = 0; nf < 8; ++nf)
        #pragma unroll
        for (int k = 0; k < 4; ++k) acc[nf][k] = 0.f;

    const int arow = w * 16 + n;
    #pragma unroll
    for (int kt = 0; kt < 6; ++kt) {
        int c = kt * 4 + q;
        int csa = (c & ~7) | ((c & 7) ^ (arow & 7));
        short8 af = *(const short8*)&Ms[(arow * 24 + csa) * 8];
        #pragma unroll
        for (int nf = 0; nf < 8; ++nf) {
            int col = nf * 16 + n;
            int csb = (c & ~7) | ((c & 7) ^ (col & 7));
            short8 bfr = *(const short8*)&Zs[(col * 24 + csb) * 8];
            acc[nf] = __builtin_amdgcn_mfma_f32_16x16x32_bf16(af, bfr, acc[nf], 0, 0, 0);
        }
    }

    const float Dd = Dp[d];
    const int i0 = w * 16 + q * 4;
    #pragma unroll
    for (int nf = 0; nf < 8; ++nf) {
        int col = nf * 16 + n;
        int bb = col >> 5, ch = col & 31;
        int cx = (i0 >> 3) ^ (col & 7);
        const ushort* zp = (const ushort*)&Zs[(col * 24 + cx) * 8 + (i0 & 7)];
        ushort o[4];
        #pragma unroll
        for (int r = 0; r < 4; ++r)
            o[r] = f2bf(acc[nf][r] + Dd * bf2f(zp[r]));
        *(uint2*)&yT[((size_t)d * BATCH + bb) * SEQ + ch * 64 + i0] = *(uint2*)o;
    }
}

// ---------------- k_gemm_ln v15: A panel from yT + B direct from global (no Bs LDS, no K-loop barriers) ----------------
// v14's per-step Bs round-trip = 80 LDS b128 ops + 2 barriers per step at 2 waves/SIMD (the
// modeled ~25 us cost). W is L2-resident across all 256 blocks; lane (q,m) needs exactly
// Wbf[o][k*32+q*8..+8] (same values v14's swizzle delivered) -> load it straight to regs,
// prefetched one step ahead. K-loop now has zero barriers and zero LDS traffic for B.
__global__ __launch_bounds__(512) void k_gemm_ln(
    const __hip_bfloat16* __restrict__ yT, const __hip_bfloat16* __restrict__ Wbf,
    const float* __restrict__ x, const float* __restrict__ bout,
    const float* __restrict__ gamma, const float* __restrict__ beta,
    float* __restrict__ out)
{
    __shared__ short Af[32][520];     // full A panel [l][kd]
    __shared__ float red[8][32][2];
    __shared__ float stats[32][2];

    const int tid  = threadIdx.x;
    const int w    = tid >> 6;
    const int lane = tid & 63;
    const int q    = lane >> 4;
    const int m    = lane & 15;
    const int r0   = blockIdx.x * 32;
    const int bq   = r0 >> 11;           // batch index (r0 32-aligned, no straddle)
    const int l0   = r0 & 2047;

    // ---- one-time A panel from yT[d][b][l]: thread (kdb, lg) reads 8 overlapped uint2 ----
    {
        const int kdb = tid >> 3, lg = (tid & 7) * 4;
        uint2 u[8];
        #pragma unroll
        for (int j = 0; j < 8; ++j)
            u[j] = *(const uint2*)&yT[((size_t)(j * 64 + kdb) * BATCH + bq) * SEQ + l0 + lg];
        #pragma unroll
        for (int j = 0; j < 8; ++j) {
            int kd = j * 64 + kdb;
            Af[lg + 0][kd] = (short)(u[j].x & 0xffff);
            Af[lg + 1][kd] = (short)(u[j].x >> 16);
            Af[lg + 2][kd] = (short)(u[j].y & 0xffff);
            Af[lg + 3][kd] = (short)(u[j].y >> 16);
        }
    }

    // ---- B frags direct from global: lane (q,m) of wave w, frag nf -> Wbf[w*64+nf*16+m][k*32+q*8] ----
    const __hip_bfloat16* wp = Wbf + (size_t)(w * 64 + m) * DM + q * 8;

    short8 bc0 = *(const short8*)(wp);
    short8 bc1 = *(const short8*)(wp + 16 * DM);
    short8 bc2 = *(const short8*)(wp + 32 * DM);
    short8 bc3 = *(const short8*)(wp + 48 * DM);

    __syncthreads();                      // Af visible to all waves

    f32x4 acc[2][4];
    #pragma unroll
    for (int a = 0; a < 2; ++a)
        #pragma unroll
        for (int nn = 0; nn < 4; ++nn)
            #pragma unroll
            for (int k = 0; k < 4; ++k) acc[a][nn][k] = 0.f;

    for (int k = 0; k < 16; ++k) {
        short8 bn0, bn1, bn2, bn3;
        if (k < 15) {                     // prefetch next step's frags (lands under MFMAs)
            const int ko = (k + 1) * 32;
            bn0 = *(const short8*)(wp + ko);
            bn1 = *(const short8*)(wp + 16 * DM + ko);
            bn2 = *(const short8*)(wp + 32 * DM + ko);
            bn3 = *(const short8*)(wp + 48 * DM + ko);
        }
        const int k0 = k * 32;
        short8 a0 = *(const short8*)&Af[m][k0 + q * 8];
        short8 a1 = *(const short8*)&Af[16 + m][k0 + q * 8];
        acc[0][0] = __builtin_amdgcn_mfma_f32_16x16x32_bf16(a0, bc0, acc[0][0], 0, 0, 0);
        acc[1][0] = __builtin_amdgcn_mfma_f32_16x16x32_bf16(a1, bc0, acc[1][0], 0, 0, 0);
        acc[0][1] = __builtin_amdgcn_mfma_f32_16x16x32_bf16(a0, bc1, acc[0][1], 0, 0, 0);
        acc[1][1] = __builtin_amdgcn_mfma_f32_16x16x32_bf16(a1, bc1, acc[1][1], 0, 0, 0);
        acc[0][2] = __builtin_amdgcn_mfma_f32_16x16x32_bf16(a0, bc2, acc[0][2], 0, 0, 0);
        acc[1][2] = __builtin_amdgcn_mfma_f32_16x16x32_bf16(a1, bc2, acc[1][2], 0, 0, 0);
        acc[0][3] = __builtin_amdgcn_mfma_f32_16x16x32_bf16(a0, bc3, acc[0][3], 0, 0, 0);
        acc[1][3] = __builtin_amdgcn_mfma_f32_16x16x32_bf16(a1, bc3, acc[1][3], 0, 0, 0);
        if (k < 15) { bc0 = bn0; bc1 = bn1; bc2 = bn2; bc3 = bn3; }
    }

    // ---- epilogue: +bias, +x residual, row mean/var, normalize ----
    float bo[4], ga[4], be[4];
    #pragma unroll
    for (int nf = 0; nf < 4; ++nf) {
        int o = w * 64 + nf * 16 + m;
        bo[nf] = bout[o]; ga[nf] = gamma[o]; be[nf] = beta[o];
    }

    float rs[2][4], rq[2][4];
    #pragma unroll
    for (int mf = 0; mf < 2; ++mf)
        #pragma unroll
        for (int i = 0; i < 4; ++i) { rs[mf][i] = 0.f; rq[mf][i] = 0.f; }

    #pragma unroll
    for (int mf = 0; mf < 2; ++mf)
        #pragma unroll
        for (int nf = 0; nf < 4; ++nf) {
            int o = w * 64 + nf * 16 + m;
            #pragma unroll
            for (int i = 0; i < 4; ++i) {
                int row = mf * 16 + q * 4 + i;    // C/D: row=(lane>>4)*4+reg, col=lane&15
                float zv = acc[mf][nf][i] + bo[nf] + x[(size_t)(r0 + row) * DM + o];
                acc[mf][nf][i] = zv;
                rs[mf][i] += zv;
                rq[mf][i] += zv * zv;
            }
        }

    #pragma unroll
    for (int mask = 1; mask < 16; mask <<= 1) {
        #pragma unroll
        for (int mf = 0; mf < 2; ++mf)
            #pragma unroll
            for (int i = 0; i < 4; ++i) {
                rs[mf][i] += __shfl_xor(rs[mf][i], mask);
                rq[mf][i] += __shfl_xor(rq[mf][i], mask);
            }
    }
    if (m == 0) {
        #pragma unroll
        for (int mf = 0; mf < 2; ++mf)
            #pragma unroll
            for (int i = 0; i < 4; ++i) {
                int row = mf * 16 + q * 4 + i;
                red[w][row][0] = rs[mf][i];
                red[w][row][1] = rq[mf][i];
            }
    }
    __syncthreads();
    if (tid < 32) {
        float s = 0.f, sq = 0.f;
        #pragma unroll
        for (int ww = 0; ww < 8; ++ww) { s += red[ww][tid][0]; sq += red[ww][tid][1]; }
        float mu  = s * (1.f / DM);
        float var = sq * (1.f / DM) - mu * mu;
        stats[tid][0] = mu;
        stats[tid][1] = 1.f / sqrtf(var + LN_EPS);
    }
    __syncthreads();

    #pragma unroll
    for (int mf = 0; mf < 2; ++mf)
        #pragma unroll
        for (int i = 0; i < 4; ++i) {
            int row = mf * 16 + q * 4 + i;
            float mu = stats[row][0], rstd = stats[row][1];
            #pragma unroll
            for (int nf = 0; nf < 4; ++nf) {
                int o = w * 64 + nf * 16 + m;
                out[(size_t)(r0 + row) * DM + o] =
                    ga[nf] * (acc[mf][nf][i] - mu) * rstd + be[nf];
            }
        }
}

// ---------------- launcher ----------------
extern "C" void kernel_launch(void* const* d_in, const int* in_sizes, int n_in,
                              void* d_out, int out_size, void* d_ws, size_t ws_size,
                              hipStream_t stream)
{
    const float* x    = (const float*)d_in[0];
    const float* logA = (const float*)d_in[1];
    const float* Aim  = (const float*)d_in[2];
    const float* Bp   = (const float*)d_in[3];
    const float* Cp   = (const float*)d_in[4];
    const float* Dp   = (const float*)d_in[5];
    const float* W    = (const float*)d_in[6];
    const float* bo   = (const float*)d_in[7];
    const float* ga   = (const float*)d_in[8];
    const float* be   = (const float*)d_in[9];

    char* ws = (char*)d_ws;
    __hip_bfloat16* Wbf = (__hip_bfloat16*)ws;                   // 512 KiB @ 0
    __hip_bfloat16* xT  = (__hip_bfloat16*)(ws + (3u << 20));    // 8 MiB    @ 3M
    __hip_bfloat16* Mt  = (__hip_bfloat16*)(ws + (11u << 20));   // 12.6 MiB @ 11M
    __hip_bfloat16* yT  = (__hip_bfloat16*)(ws + (41u << 20));   // 8 MiB    @ 41M
    __hip_bfloat16* Gt  = (__hip_bfloat16*)(ws + (57u << 20));   // 8 MiB    @ 57M
    float2* e64         = (float2*)(ws + (65u << 20));           // 256 KiB  @ 65M

    k_prep   <<<3200, 256, 0, stream>>>(x, logA, Aim, Bp, Cp, W, xT, Wbf, Mt, Gt, e64);
    k_ssm    <<<DM, 256, 0, stream>>>(Gt, Mt, xT, e64, Dp, yT);
    k_gemm_ln<<<(BATCH * SEQ) / 32, 512, 0, stream>>>(yT, Wbf, x, bo, ga, be, (float*)d_out);
}